// Round 2
// baseline (357.462 us; speedup 1.0000x reference)
//
#include <hip/hip_runtime.h>
#include <stdint.h>

// Problem constants (CorrelationModule): x[8,384,48,48], O=512, N=48*48=2304
#define B_    8
#define CIN   384
#define OCH   512
#define NTOK  2304
#define SCALE 0.044194173824159216f  // 1/sqrt(512)

typedef unsigned short u16;
typedef u16   u16x8 __attribute__((ext_vector_type(8)));
typedef short s16x8 __attribute__((ext_vector_type(8)));
typedef float f32x4 __attribute__((ext_vector_type(4)));

// ---------- bf16 helpers (bit-level, RNE) ----------
__device__ __forceinline__ u16 f2bf(float f) {
    union { uint32_t i; float f; } v; v.f = f;
    uint32_t r = v.i + 0x7fffu + ((v.i >> 16) & 1u);
    return (u16)(r >> 16);
}

// ---------- async global->LDS (width 16) ----------
typedef __attribute__((address_space(1))) const uint32_t glb_u32;
typedef __attribute__((address_space(3))) uint32_t lds_u32;

// =====================================================================
// BRICK FORMAT for all bf16 intermediates.
// brick (g, c) = rows g*16..+16, cols c*32..+32, 512 u16, chunk l (16 B)
// = (col8 = l>>4, row = l&15).  u16 offset of (row, col) inside brick:
//   ((col>>3)&3)*128 + (row&15)*8 + (col&7)
// R8 LDS-repack epilogue REVERTED (R8 post-mortem: +3 barriers + 8-way
// LDS aliasing made it a net loss; direct 2-B brick stores are absorbed
// by L2 write-back fine).
// =====================================================================
__device__ __forceinline__ size_t baddr(int row, int col, int Kc) {
    return ((size_t)(row >> 4) * (Kc >> 5) + (col >> 5)) * 512
         + (size_t)(((col >> 3) & 3) * 128 + (row & 15) * 8 + (col & 7));
}

// stage a 128x32 brick-format tile (rows row0..+128, cols k0..+32) into LDS
__device__ __forceinline__ void stage_blocked(const u16* __restrict__ base,
                                              int row0, int k0, int Kc,
                                              u16* __restrict__ dst, int t)
{
    const int lane = t & 63;
    const int w = t >> 6;
    const int bpr = Kc >> 5;
#pragma unroll
    for (int it = 0; it < 2; ++it) {
        const int ck = w * 2 + it;               // 0..7 (16-row groups)
        const u16* gp = base + ((size_t)((row0 >> 4) + ck) * bpr + (k0 >> 5)) * 512
                      + (size_t)lane * 8;
        u16* lp = dst + ck * 512;                // wave-uniform base
        __builtin_amdgcn_global_load_lds((glb_u32*)gp, (lds_u32*)lp, 16, 0, 0);
    }
}

// 2x2-wave 128x128 MFMA core (16 MFMA/wave per BK=32 step; proven R6/R7)
__device__ __forceinline__ void mfma_core(const u16* __restrict__ As,
                                          const u16* __restrict__ Bs,
                                          int wm16, int wn16, int lrow, int kq,
                                          f32x4 acc[4][4])
{
    s16x8 a[4], b[4];
#pragma unroll
    for (int i = 0; i < 4; ++i)
        a[i] = *(const s16x8*)(As + (((wm16 + i) * 64) + kq * 16 + lrow) * 8);
#pragma unroll
    for (int j = 0; j < 4; ++j)
        b[j] = *(const s16x8*)(Bs + (((wn16 + j) * 64) + kq * 16 + lrow) * 8);
#pragma unroll
    for (int i = 0; i < 4; ++i)
#pragma unroll
        for (int j = 0; j < 4; ++j)
            acc[i][j] = __builtin_amdgcn_mfma_f32_16x16x32_bf16(a[i], b[j], acc[i][j], 0, 0, 0);
}

// =====================================================================
// R9: double-buffered prefetch K-loop (T3-minimum).  All kernels were
// latency-bound (MfmaUtil 17-23, VALUBusy 10-28, HBM 10-22, occ 12-26:
// no pipe busy).  Old loop exposed full global_load_lds latency per
// BK=32 step (compiler pins vmcnt(0) to the barrier).  Now next-tile
// loads issue BEFORE current-tile MFMA -> the vmcnt(0)@barrier waits on
// loads covered by ~400 cyc of ds_read+MFMA.  One barrier/step (was 2).
// Distinct named buffers (As0/As1) so alias analysis can't pin an early
// vmcnt(0) before the ds_reads.  Requires K%64==0 (384/512/2304 all ok).
// =====================================================================
#define KLOOP_DBUF(A_, B_, m0_, n0_, K_)                                   \
    stage_blocked(A_, m0_, 0, K_, As0, t);                                 \
    stage_blocked(B_, n0_, 0, K_, Bs0, t);                                 \
    __syncthreads();                                                       \
    for (int p = 0; p < (K_) / 64 - 1; ++p) {                              \
        stage_blocked(A_, m0_, p * 64 + 32, K_, As1, t);                   \
        stage_blocked(B_, n0_, p * 64 + 32, K_, Bs1, t);                   \
        mfma_core(As0, Bs0, wm16, wn16, lrow, kq, acc);                    \
        __syncthreads();                                                   \
        stage_blocked(A_, m0_, p * 64 + 64, K_, As0, t);                   \
        stage_blocked(B_, n0_, p * 64 + 64, K_, Bs0, t);                   \
        mfma_core(As1, Bs1, wm16, wn16, lrow, kq, acc);                    \
        __syncthreads();                                                   \
    }                                                                      \
    stage_blocked(A_, m0_, (K_) - 32, K_, As1, t);                         \
    stage_blocked(B_, n0_, (K_) - 32, K_, Bs1, t);                         \
    mfma_core(As0, Bs0, wm16, wn16, lrow, kq, acc);                        \
    __syncthreads();                                                       \
    mfma_core(As1, Bs1, wm16, wn16, lrow, kq, acc);

// =====================================================================
// Kernel 0a: weight cast fp32 -> bf16, BRICK output.
// =====================================================================
#define WQKV_SZ (OCH * CIN)
#define WO_SZ   (OCH * OCH)
#define CH_QKV  (WQKV_SZ / 8)
#define CH_WO   (WO_SZ / 8)
#define CH_TOT  (3 * CH_QKV + CH_WO)

__global__ __launch_bounds__(256) void prep_w_kernel(
    const float* __restrict__ Wq, const float* __restrict__ Wk,
    const float* __restrict__ Wv, const float* __restrict__ Wo,
    u16* __restrict__ Wqb, u16* __restrict__ Wkb,
    u16* __restrict__ Wvb, u16* __restrict__ Wob)
{
    int lc = blockIdx.x * 256 + threadIdx.x;
    if (lc >= CH_TOT) return;
    const float* src; u16* dst; int Kc;
    if      (lc < CH_QKV)     { src = Wq; dst = Wqb; Kc = CIN; }
    else if (lc < 2 * CH_QKV) { src = Wk; dst = Wkb; Kc = CIN; lc -= CH_QKV; }
    else if (lc < 3 * CH_QKV) { src = Wv; dst = Wvb; Kc = CIN; lc -= 2 * CH_QKV; }
    else                      { src = Wo; dst = Wob; Kc = OCH; lc -= 3 * CH_QKV; }
    const int brick = lc >> 6, l = lc & 63;
    const int bpr = Kc >> 5;
    const int g = brick / bpr, c = brick % bpr;
    const int row = g * 16 + (l & 15);
    const int col = c * 32 + (l >> 4) * 8;
    const float* s = src + (size_t)row * Kc + col;
    float4 v0 = *(const float4*)s;
    float4 v1 = *(const float4*)(s + 4);
    u16x8 o;
    o[0] = f2bf(v0.x); o[1] = f2bf(v0.y); o[2] = f2bf(v0.z); o[3] = f2bf(v0.w);
    o[4] = f2bf(v1.x); o[5] = f2bf(v1.y); o[6] = f2bf(v1.z); o[7] = f2bf(v1.w);
    *(u16x8*)(dst + (size_t)lc * 8) = o;
}

// =====================================================================
// Kernel 0b: transpose x [B,C,N] fp32 -> xT [B,N,C] bf16 BRICK.
// =====================================================================
__global__ __launch_bounds__(256) void transpose_x_kernel(
    const float* __restrict__ x, u16* __restrict__ xT)
{
    const int n0 = blockIdx.x * 64;
    const int c0 = blockIdx.y * 64;
    const int b  = blockIdx.z;
    const float* X = x + (size_t)b * CIN * NTOK;

    __shared__ float Ts[64][66];

    const int t = threadIdx.x;
#pragma unroll
    for (int rep = 0; rep < 4; ++rep) {
        const int cr = (t >> 4) + rep * 16;
        const int n4 = (t & 15) * 4;
        float4 v = *(const float4*)(X + (size_t)(c0 + cr) * NTOK + n0 + n4);
        *(float2*)&Ts[cr][n4]     = make_float2(v.x, v.y);
        *(float2*)&Ts[cr][n4 + 2] = make_float2(v.z, v.w);
    }
    __syncthreads();

    u16* O = xT + (size_t)b * NTOK * CIN;
#pragma unroll
    for (int rep = 0; rep < 2; ++rep) {
        const int nr = (t >> 3) + rep * 32;
        const int c8 = (t & 7) * 8;
        u16 tmp[8];
#pragma unroll
        for (int j = 0; j < 8; ++j) tmp[j] = f2bf(Ts[c8 + j][nr]);
        *(u16x8*)(O + baddr(n0 + nr, c0 + c8, CIN)) = *(const u16x8*)tmp;
    }
}

// =====================================================================
// Merged Q+K projection (128x128, brick in/out): z = which*8 + batch.
// =====================================================================
__global__ __launch_bounds__(256) void qk_kernel(
    const u16* __restrict__ xT,
    const u16* __restrict__ Wqb, const float* __restrict__ bq,
    const u16* __restrict__ Wkb, const float* __restrict__ bk,
    u16* __restrict__ Qt, u16* __restrict__ Kt)
{
    const int zz  = blockIdx.x % 16;
    const int b   = zz & 7, which = zz >> 3;
    const int rem = blockIdx.x / 16;
    const int n0 = (rem % 4) * 128;
    const int m0 = (rem / 4) * 128;
    const u16* A  = xT + (size_t)b * NTOK * CIN;
    const u16* Bp = which ? Wkb : Wqb;
    const float* bias = which ? bk : bq;
    u16* C = (which ? Kt : Qt) + (size_t)b * NTOK * OCH;

    __shared__ u16 As0[128 * 32], As1[128 * 32];
    __shared__ u16 Bs0[128 * 32], Bs1[128 * 32];

    const int t = threadIdx.x;
    const int w = t >> 6, ln = t & 63;
    const int wm16 = (w & 1) * 4, wn16 = (w >> 1) * 4;
    const int lrow = ln & 15, kq = ln >> 4;

    f32x4 acc[4][4] = {};

    KLOOP_DBUF(A, Bp, m0, n0, CIN)

#pragma unroll
    for (int i = 0; i < 4; ++i) {
        const int row = m0 + (wm16 + i) * 16 + kq * 4;
#pragma unroll
        for (int r = 0; r < 4; ++r)
#pragma unroll
            for (int j = 0; j < 4; ++j) {
                const int col = n0 + (wn16 + j) * 16 + lrow;
                C[baddr(row + r, col, OCH)] = f2bf(acc[i][j][r] + bias[col]);
            }
    }
}

// =====================================================================
// Generic MFMA GEMM (128x128, brick A/B): C[m][n] = sum_k A[m][k]*B[n][k]
// BIAS: 1 row bias.  OutT u16 -> brick C; float -> row-major C.
// =====================================================================
template <int BIAS, typename OutT>
__global__ __launch_bounds__(256) void gemm_kernel(
    const u16* __restrict__ Ag, const u16* __restrict__ Bg,
    const float* __restrict__ bias, OutT* __restrict__ Cg,
    int K, int N, long sA, long sB, long sC, int GX, int GZ)
{
    const int z   = blockIdx.x % GZ;
    const int rem = blockIdx.x / GZ;
    const int n0 = (rem % GX) * 128;
    const int m0 = (rem / GX) * 128;
    const u16* A  = Ag + (size_t)z * sA;
    const u16* Bp = Bg + (size_t)z * sB;
    OutT* C = Cg + (size_t)z * sC;

    __shared__ u16 As0[128 * 32], As1[128 * 32];
    __shared__ u16 Bs0[128 * 32], Bs1[128 * 32];

    const int t = threadIdx.x;
    const int w = t >> 6, ln = t & 63;
    const int wm16 = (w & 1) * 4, wn16 = (w >> 1) * 4;
    const int lrow = ln & 15, kq = ln >> 4;

    f32x4 acc[4][4] = {};

    KLOOP_DBUF(A, Bp, m0, n0, K)

#pragma unroll
    for (int i = 0; i < 4; ++i) {
        const int row = m0 + (wm16 + i) * 16 + kq * 4;
#pragma unroll
        for (int r = 0; r < 4; ++r) {
            float badd = 0.f;
            if (BIAS == 1) badd = bias[row + r];
#pragma unroll
            for (int j = 0; j < 4; ++j) {
                const int col = n0 + (wn16 + j) * 16 + lrow;
                float v = acc[i][j][r] + badd;
                if constexpr (sizeof(OutT) == 2)
                    C[baddr(row + r, col, N)] = f2bf(v);
                else
                    C[(size_t)(row + r) * N + col] = v;
            }
        }
    }
}

// =====================================================================
// Logits+exp kernel (128x128, brick): E[n][m] = exp(SCALE * Qt[n].Kt[m]);
// rowsumG[z][n] += partial row sums (fp32 device atomics).
// =====================================================================
__global__ __launch_bounds__(256) void logits_exp_kernel(
    const u16* __restrict__ Qt, const u16* __restrict__ Kt,
    u16* __restrict__ Ew, float* __restrict__ rowsumG)
{
    const int z   = blockIdx.x % B_;
    const int rem = blockIdx.x / B_;
    const int n0 = (rem % (NTOK / 128)) * 128;   // Kt token tiles, fast
    const int m0 = (rem / (NTOK / 128)) * 128;   // Qt token tiles
    const u16* A  = Qt + (size_t)z * NTOK * OCH;
    const u16* Bp = Kt + (size_t)z * NTOK * OCH;

    __shared__ u16 As0[128 * 32], As1[128 * 32];
    __shared__ u16 Bs0[128 * 32], Bs1[128 * 32];
    __shared__ float rowsumL[128];

    const int t = threadIdx.x;
    const int w = t >> 6, ln = t & 63;
    const int wm16 = (w & 1) * 4, wn16 = (w >> 1) * 4;
    const int lrow = ln & 15, kq = ln >> 4;

    if (t < 128) rowsumL[t] = 0.f;

    f32x4 acc[4][4] = {};

    KLOOP_DBUF(A, Bp, m0, n0, OCH)

    u16* E = Ew + (size_t)z * NTOK * NTOK;
#pragma unroll
    for (int i = 0; i < 4; ++i) {
        const int row = m0 + (wm16 + i) * 16 + kq * 4;
#pragma unroll
        for (int r = 0; r < 4; ++r) {
            float part = 0.f;
#pragma unroll
            for (int j = 0; j < 4; ++j) {
                const int col = n0 + (wn16 + j) * 16 + lrow;
                float e = __expf(acc[i][j][r] * SCALE);
                part += e;
                E[baddr(row + r, col, NTOK)] = f2bf(e);
            }
            part += __shfl_xor(part, 1);
            part += __shfl_xor(part, 2);
            part += __shfl_xor(part, 4);
            part += __shfl_xor(part, 8);
            if (lrow == 0) atomicAdd(&rowsumL[(wm16 + i) * 16 + kq * 4 + r], part);
        }
    }
    __syncthreads();
    if (t < 128) atomicAdd(&rowsumG[(size_t)z * NTOK + m0 + t], rowsumL[t]);
}

// =====================================================================
// PV kernel (128x128, brick): AOt[n][o] = (sum_m E[n][m]*V[o][m]) / rowsum
// =====================================================================
__global__ __launch_bounds__(256) void pv_div_kernel(
    const u16* __restrict__ Ew, const u16* __restrict__ Vw,
    const float* __restrict__ rowsumG, u16* __restrict__ AOt)
{
    const int z   = blockIdx.x % B_;
    const int rem = blockIdx.x / B_;
    const int n0 = (rem % 4) * 128;              // o tiles, fast
    const int m0 = (rem / 4) * 128;              // token tiles
    const u16* A  = Ew + (size_t)z * NTOK * NTOK;
    const u16* Bp = Vw + (size_t)z * OCH * NTOK;

    __shared__ u16 As0[128 * 32], As1[128 * 32];
    __shared__ u16 Bs0[128 * 32], Bs1[128 * 32];

    const int t = threadIdx.x;
    const int w = t >> 6, ln = t & 63;
    const int wm16 = (w & 1) * 4, wn16 = (w >> 1) * 4;
    const int lrow = ln & 15, kq = ln >> 4;

    f32x4 acc[4][4] = {};

    KLOOP_DBUF(A, Bp, m0, n0, NTOK)

    u16* AO = AOt + (size_t)z * NTOK * OCH;
#pragma unroll
    for (int i = 0; i < 4; ++i) {
        const int row = m0 + (wm16 + i) * 16 + kq * 4;
#pragma unroll
        for (int r = 0; r < 4; ++r) {
            const float inv = 1.0f / rowsumG[(size_t)z * NTOK + row + r];
#pragma unroll
            for (int j = 0; j < 4; ++j) {
                const int col = n0 + (wn16 + j) * 16 + lrow;
                AO[baddr(row + r, col, OCH)] = f2bf(acc[i][j][r] * inv);
            }
        }
    }
}

// =====================================================================
extern "C" void kernel_launch(void* const* d_in, const int* in_sizes, int n_in,
                              void* d_out, int out_size, void* d_ws, size_t ws_size,
                              hipStream_t stream)
{
    const float* x  = (const float*)d_in[0];
    const float* Wq = (const float*)d_in[1];
    const float* bq = (const float*)d_in[2];
    const float* Wk = (const float*)d_in[3];
    const float* bk = (const float*)d_in[4];
    const float* Wv = (const float*)d_in[5];
    const float* bv = (const float*)d_in[6];
    const float* Wo = (const float*)d_in[7];
    const float* bo = (const float*)d_in[8];
    float* out = (float*)d_out;

    u16* ws = (u16*)d_ws;
    u16* Wqb = ws;
    u16* Wkb = Wqb + WQKV_SZ;
    u16* Wvb = Wkb + WQKV_SZ;
    u16* Wob = Wvb + WQKV_SZ;
    u16* xT  = Wob + WO_SZ;
    const size_t xtsz  = (size_t)B_ * NTOK * CIN;
    const size_t qkvsz = (size_t)B_ * NTOK * OCH;
    u16* Qt  = xT + xtsz;
    u16* Kt  = Qt + qkvsz;
    u16* Vw  = Kt + qkvsz;
    u16* Ew  = Vw + qkvsz;                          // B*N*N
    float* rowsumG = (float*)(Ew + (size_t)B_ * NTOK * NTOK);
    u16* AOt = Qt;                                  // alias: Qt dead after logits
    // total approx 157.5 MB

    dim3 blk(256);

    prep_w_kernel<<<dim3((CH_TOT + 255) / 256), blk, 0, stream>>>(
        Wq, Wk, Wv, Wo, Wqb, Wkb, Wvb, Wob);
    transpose_x_kernel<<<dim3(NTOK / 64, CIN / 64, B_), blk, 0, stream>>>(x, xT);
    hipMemsetAsync(rowsumG, 0, (size_t)B_ * NTOK * sizeof(float), stream);

    // Q & K merged: 4 o-tiles x 18 token-tiles x 16 (which*8+batch) = 1152
    qk_kernel<<<dim3(4 * 18 * 16), blk, 0, stream>>>(
        xT, Wqb, bq, Wkb, bk, Qt, Kt);
    // V[o][m] = Wv[o].xT[m] + bv[o]: 18 n-tiles (fast) x 4 m-tiles x 8 = 576
    gemm_kernel<1, u16><<<dim3(18 * 4 * B_), blk, 0, stream>>>(
        Wvb, xT, bv, Vw, CIN, NTOK, 0L, (long)NTOK * CIN, (long)OCH * NTOK, 18, B_);

    // E = exp(scale * Qt.Kt^T), rowsumG += row sums  (18x18x8 = 2592)
    logits_exp_kernel<<<dim3(18 * 18 * B_), blk, 0, stream>>>(Qt, Kt, Ew, rowsumG);

    // AOt = (E.V^T) / rowsum: 4 o-tiles (fast) x 18 token-tiles x 8 = 576
    pv_div_kernel<<<dim3(4 * 18 * B_), blk, 0, stream>>>(Ew, Vw, rowsumG, AOt);

    // out[p][n] = Wo[p].AOt[n] + bo[p]: 18 n-tiles (fast) x 4 p-tiles x 8 = 576
    gemm_kernel<1, float><<<dim3(18 * 4 * B_), blk, 0, stream>>>(
        Wob, AOt, bo, out, OCH, NTOK, 0L, (long)NTOK * OCH, (long)OCH * NTOK, 18, B_);
}

// Round 3
// 325.918 us; speedup vs baseline: 1.0968x; 1.0968x over previous
//
#include <hip/hip_runtime.h>
#include <stdint.h>

// Problem constants (CorrelationModule): x[8,384,48,48], O=512, N=48*48=2304
#define B_    8
#define CIN   384
#define OCH   512
#define NTOK  2304
#define SCALE 0.044194173824159216f  // 1/sqrt(512)

typedef unsigned short u16;
typedef u16   u16x8 __attribute__((ext_vector_type(8)));
typedef short s16x8 __attribute__((ext_vector_type(8)));
typedef float f32x4 __attribute__((ext_vector_type(4)));

// ---------- bf16 helpers (bit-level, RNE) ----------
__device__ __forceinline__ u16 f2bf(float f) {
    union { uint32_t i; float f; } v; v.f = f;
    uint32_t r = v.i + 0x7fffu + ((v.i >> 16) & 1u);
    return (u16)(r >> 16);
}

// ---------- async global->LDS (width 16) ----------
typedef __attribute__((address_space(1))) const uint32_t glb_u32;
typedef __attribute__((address_space(3))) uint32_t lds_u32;

// =====================================================================
// BRICK FORMAT for all bf16 intermediates.
// brick (g, c) = rows g*16..+16, cols c*32..+32, 512 u16, chunk l (16 B)
// = (col8 = l>>4, row = l&15).  u16 offset of (row, col) inside brick:
//   ((col>>3)&3)*128 + (row&15)*8 + (col&7)
// R8 epilogue-repack and R9 prefetch-dbuf both REVERTED (regressions).
// R10: exact R0 schedule (stage; barrier; mfma; barrier) with BK=64
// (2 brick-cols/step, mfma_core x2) -> half the barrier drains, plus
// pointer-increment staging and hoisted epilogue addressing (VALU cut).
// =====================================================================
__device__ __forceinline__ size_t baddr(int row, int col, int Kc) {
    return ((size_t)(row >> 4) * (Kc >> 5) + (col >> 5)) * 512
         + (size_t)(((col >> 3) & 3) * 128 + (row & 15) * 8 + (col & 7));
}

// stage one 128x64 tile half (2 brick-cols) for this thread.
// pA: per-thread src for brick-row (base>>4)+w*2, brick-col cc0 (lane*8
// included).  rs = one brick-row stride in u16 = (K>>5)*512.
// LDS image: [cc][ck*512] with cc blocks 4096 u16 apart.
__device__ __forceinline__ void stage64(const u16* __restrict__ pA, size_t rs,
                                        u16* __restrict__ dst, int w)
{
    u16* lp = dst + w * 1024;
    __builtin_amdgcn_global_load_lds((glb_u32*)pA,              (lds_u32*)lp,           16, 0, 0);
    __builtin_amdgcn_global_load_lds((glb_u32*)(pA + rs),       (lds_u32*)(lp + 512),   16, 0, 0);
    __builtin_amdgcn_global_load_lds((glb_u32*)(pA + 512),      (lds_u32*)(lp + 4096),  16, 0, 0);
    __builtin_amdgcn_global_load_lds((glb_u32*)(pA + rs + 512), (lds_u32*)(lp + 4608),  16, 0, 0);
}

// 2x2-wave 128x128 MFMA core (16 MFMA/wave per BK=32 half; proven R6/R7)
__device__ __forceinline__ void mfma_core(const u16* __restrict__ As,
                                          const u16* __restrict__ Bs,
                                          int wm16, int wn16, int lrow, int kq,
                                          f32x4 acc[4][4])
{
    s16x8 a[4], b[4];
#pragma unroll
    for (int i = 0; i < 4; ++i)
        a[i] = *(const s16x8*)(As + (((wm16 + i) * 64) + kq * 16 + lrow) * 8);
#pragma unroll
    for (int j = 0; j < 4; ++j)
        b[j] = *(const s16x8*)(Bs + (((wn16 + j) * 64) + kq * 16 + lrow) * 8);
#pragma unroll
    for (int i = 0; i < 4; ++i)
#pragma unroll
        for (int j = 0; j < 4; ++j)
            acc[i][j] = __builtin_amdgcn_mfma_f32_16x16x32_bf16(a[i], b[j], acc[i][j], 0, 0, 0);
}

// BK=64 K-loop, R0 schedule shape (stage; barrier; mfma; barrier).
// Running per-thread pointers advance 1024 u16 (2 brick-cols) per step.
#define KLOOP64(Abase, Bbase, m0_, n0_, K_)                                    \
    {                                                                          \
        const size_t rs_ = (size_t)((K_) >> 5) * 512;                          \
        const u16* pA_ = (Abase)                                               \
            + (size_t)((((m0_) >> 4) + w * 2) * ((K_) >> 5)) * 512             \
            + (size_t)ln * 8;                                                  \
        const u16* pB_ = (Bbase)                                               \
            + (size_t)((((n0_) >> 4) + w * 2) * ((K_) >> 5)) * 512             \
            + (size_t)ln * 8;                                                  \
        for (int k0_ = 0; k0_ < (K_); k0_ += 64) {                             \
            stage64(pA_, rs_, As, w);                                          \
            stage64(pB_, rs_, Bs, w);                                          \
            __syncthreads();                                                   \
            mfma_core(As, Bs, wm16, wn16, lrow, kq, acc);                      \
            mfma_core(As + 4096, Bs + 4096, wm16, wn16, lrow, kq, acc);        \
            __syncthreads();                                                   \
            pA_ += 1024; pB_ += 1024;                                          \
        }                                                                      \
    }

// =====================================================================
// Kernel 0a: weight cast fp32 -> bf16, BRICK output.
// =====================================================================
#define WQKV_SZ (OCH * CIN)
#define WO_SZ   (OCH * OCH)
#define CH_QKV  (WQKV_SZ / 8)
#define CH_WO   (WO_SZ / 8)
#define CH_TOT  (3 * CH_QKV + CH_WO)

__global__ __launch_bounds__(256) void prep_w_kernel(
    const float* __restrict__ Wq, const float* __restrict__ Wk,
    const float* __restrict__ Wv, const float* __restrict__ Wo,
    u16* __restrict__ Wqb, u16* __restrict__ Wkb,
    u16* __restrict__ Wvb, u16* __restrict__ Wob)
{
    int lc = blockIdx.x * 256 + threadIdx.x;
    if (lc >= CH_TOT) return;
    const float* src; u16* dst; int Kc;
    if      (lc < CH_QKV)     { src = Wq; dst = Wqb; Kc = CIN; }
    else if (lc < 2 * CH_QKV) { src = Wk; dst = Wkb; Kc = CIN; lc -= CH_QKV; }
    else if (lc < 3 * CH_QKV) { src = Wv; dst = Wvb; Kc = CIN; lc -= 2 * CH_QKV; }
    else                      { src = Wo; dst = Wob; Kc = OCH; lc -= 3 * CH_QKV; }
    const int brick = lc >> 6, l = lc & 63;
    const int bpr = Kc >> 5;
    const int g = brick / bpr, c = brick % bpr;
    const int row = g * 16 + (l & 15);
    const int col = c * 32 + (l >> 4) * 8;
    const float* s = src + (size_t)row * Kc + col;
    float4 v0 = *(const float4*)s;
    float4 v1 = *(const float4*)(s + 4);
    u16x8 o;
    o[0] = f2bf(v0.x); o[1] = f2bf(v0.y); o[2] = f2bf(v0.z); o[3] = f2bf(v0.w);
    o[4] = f2bf(v1.x); o[5] = f2bf(v1.y); o[6] = f2bf(v1.z); o[7] = f2bf(v1.w);
    *(u16x8*)(dst + (size_t)lc * 8) = o;
}

// =====================================================================
// Kernel 0b: transpose x [B,C,N] fp32 -> xT [B,N,C] bf16 BRICK.
// =====================================================================
__global__ __launch_bounds__(256) void transpose_x_kernel(
    const float* __restrict__ x, u16* __restrict__ xT)
{
    const int n0 = blockIdx.x * 64;
    const int c0 = blockIdx.y * 64;
    const int b  = blockIdx.z;
    const float* X = x + (size_t)b * CIN * NTOK;

    __shared__ float Ts[64][66];

    const int t = threadIdx.x;
#pragma unroll
    for (int rep = 0; rep < 4; ++rep) {
        const int cr = (t >> 4) + rep * 16;
        const int n4 = (t & 15) * 4;
        float4 v = *(const float4*)(X + (size_t)(c0 + cr) * NTOK + n0 + n4);
        *(float2*)&Ts[cr][n4]     = make_float2(v.x, v.y);
        *(float2*)&Ts[cr][n4 + 2] = make_float2(v.z, v.w);
    }
    __syncthreads();

    u16* O = xT + (size_t)b * NTOK * CIN;
#pragma unroll
    for (int rep = 0; rep < 2; ++rep) {
        const int nr = (t >> 3) + rep * 32;
        const int c8 = (t & 7) * 8;
        u16 tmp[8];
#pragma unroll
        for (int j = 0; j < 8; ++j) tmp[j] = f2bf(Ts[c8 + j][nr]);
        *(u16x8*)(O + baddr(n0 + nr, c0 + c8, CIN)) = *(const u16x8*)tmp;
    }
}

// =====================================================================
// Merged Q+K projection (128x128, brick in/out): z = which*8 + batch.
// =====================================================================
__global__ __launch_bounds__(256) void qk_kernel(
    const u16* __restrict__ xT,
    const u16* __restrict__ Wqb, const float* __restrict__ bq,
    const u16* __restrict__ Wkb, const float* __restrict__ bk,
    u16* __restrict__ Qt, u16* __restrict__ Kt)
{
    const int zz  = blockIdx.x % 16;
    const int b   = zz & 7, which = zz >> 3;
    const int rem = blockIdx.x / 16;
    const int n0 = (rem % 4) * 128;
    const int m0 = (rem / 4) * 128;
    const u16* A  = xT + (size_t)b * NTOK * CIN;
    const u16* Bp = which ? Wkb : Wqb;
    const float* bias = which ? bk : bq;
    u16* C = (which ? Kt : Qt) + (size_t)b * NTOK * OCH;

    __shared__ u16 As[8192];
    __shared__ u16 Bs[8192];

    const int t = threadIdx.x;
    const int w = t >> 6, ln = t & 63;
    const int wm16 = (w & 1) * 4, wn16 = (w >> 1) * 4;
    const int lrow = ln & 15, kq = ln >> 4;

    f32x4 acc[4][4] = {};

    KLOOP64(A, Bp, m0, n0, CIN)

    // hoisted brick addressing: addr = base_i + c_j*512 + (j&1)*256 + offl + r*8
    const int offl = ((lrow >> 3) << 7) + (lrow & 7) + (kq << 5);
    float bcol[4];
#pragma unroll
    for (int j = 0; j < 4; ++j)
        bcol[j] = bias[n0 + (wn16 + j) * 16 + lrow];
#pragma unroll
    for (int i = 0; i < 4; ++i) {
        u16* Crow = C + ((size_t)((m0 >> 4) + wm16 + i) * (OCH >> 5) + (n0 >> 5)) * 512 + offl;
#pragma unroll
        for (int j = 0; j < 4; ++j) {
            u16* Cj = Crow + ((wn16 + j) >> 1) * 512 + ((j & 1) << 8);
#pragma unroll
            for (int r = 0; r < 4; ++r)
                Cj[r * 8] = f2bf(acc[i][j][r] + bcol[j]);
        }
    }
}

// =====================================================================
// Generic MFMA GEMM (128x128, brick A/B): C[m][n] = sum_k A[m][k]*B[n][k]
// BIAS: 1 row bias.  OutT u16 -> brick C; float -> row-major C.
// =====================================================================
template <int BIAS, typename OutT>
__global__ __launch_bounds__(256) void gemm_kernel(
    const u16* __restrict__ Ag, const u16* __restrict__ Bg,
    const float* __restrict__ bias, OutT* __restrict__ Cg,
    int K, int N, long sA, long sB, long sC, int GX, int GZ)
{
    const int z   = blockIdx.x % GZ;
    const int rem = blockIdx.x / GZ;
    const int n0 = (rem % GX) * 128;
    const int m0 = (rem / GX) * 128;
    const u16* A  = Ag + (size_t)z * sA;
    const u16* Bp = Bg + (size_t)z * sB;
    OutT* C = Cg + (size_t)z * sC;

    __shared__ u16 As[8192];
    __shared__ u16 Bs[8192];

    const int t = threadIdx.x;
    const int w = t >> 6, ln = t & 63;
    const int wm16 = (w & 1) * 4, wn16 = (w >> 1) * 4;
    const int lrow = ln & 15, kq = ln >> 4;

    f32x4 acc[4][4] = {};

    KLOOP64(A, Bp, m0, n0, K)

    if constexpr (sizeof(OutT) == 2) {
        const int offl = ((lrow >> 3) << 7) + (lrow & 7) + (kq << 5);
#pragma unroll
        for (int i = 0; i < 4; ++i) {
            float4 b4 = make_float4(0.f, 0.f, 0.f, 0.f);
            if (BIAS == 1)
                b4 = *(const float4*)(bias + m0 + (wm16 + i) * 16 + kq * 4);
            u16* Crow = (u16*)C + ((size_t)((m0 >> 4) + wm16 + i) * (N >> 5) + (n0 >> 5)) * 512 + offl;
#pragma unroll
            for (int j = 0; j < 4; ++j) {
                u16* Cj = Crow + ((wn16 + j) >> 1) * 512 + ((j & 1) << 8);
                Cj[0]  = f2bf(acc[i][j][0] + b4.x);
                Cj[8]  = f2bf(acc[i][j][1] + b4.y);
                Cj[16] = f2bf(acc[i][j][2] + b4.z);
                Cj[24] = f2bf(acc[i][j][3] + b4.w);
            }
        }
    } else {
#pragma unroll
        for (int i = 0; i < 4; ++i) {
            const int row = m0 + (wm16 + i) * 16 + kq * 4;
#pragma unroll
            for (int r = 0; r < 4; ++r) {
                float badd = 0.f;
                if (BIAS == 1) badd = bias[row + r];
#pragma unroll
                for (int j = 0; j < 4; ++j) {
                    const int col = n0 + (wn16 + j) * 16 + lrow;
                    C[(size_t)(row + r) * N + col] = acc[i][j][r] + badd;
                }
            }
        }
    }
}

// =====================================================================
// Logits+exp kernel (128x128, brick): E[n][m] = exp(SCALE * Qt[n].Kt[m]);
// rowsumG[z][n] += partial row sums (fp32 device atomics).
// =====================================================================
__global__ __launch_bounds__(256) void logits_exp_kernel(
    const u16* __restrict__ Qt, const u16* __restrict__ Kt,
    u16* __restrict__ Ew, float* __restrict__ rowsumG)
{
    const int z   = blockIdx.x % B_;
    const int rem = blockIdx.x / B_;
    const int n0 = (rem % (NTOK / 128)) * 128;   // Kt token tiles, fast
    const int m0 = (rem / (NTOK / 128)) * 128;   // Qt token tiles
    const u16* A  = Qt + (size_t)z * NTOK * OCH;
    const u16* Bp = Kt + (size_t)z * NTOK * OCH;

    __shared__ u16 As[8192];
    __shared__ u16 Bs[8192];
    __shared__ float rowsumL[128];

    const int t = threadIdx.x;
    const int w = t >> 6, ln = t & 63;
    const int wm16 = (w & 1) * 4, wn16 = (w >> 1) * 4;
    const int lrow = ln & 15, kq = ln >> 4;

    if (t < 128) rowsumL[t] = 0.f;

    f32x4 acc[4][4] = {};

    KLOOP64(A, Bp, m0, n0, OCH)

    u16* E = Ew + (size_t)z * NTOK * NTOK;
    const int offl = ((lrow >> 3) << 7) + (lrow & 7) + (kq << 5);
#pragma unroll
    for (int i = 0; i < 4; ++i) {
        u16* Erow = E + ((size_t)((m0 >> 4) + wm16 + i) * (NTOK >> 5) + (n0 >> 5)) * 512 + offl;
#pragma unroll
        for (int r = 0; r < 4; ++r) {
            float part = 0.f;
#pragma unroll
            for (int j = 0; j < 4; ++j) {
                float e = __expf(acc[i][j][r] * SCALE);
                part += e;
                Erow[((wn16 + j) >> 1) * 512 + ((j & 1) << 8) + r * 8] = f2bf(e);
            }
            part += __shfl_xor(part, 1);
            part += __shfl_xor(part, 2);
            part += __shfl_xor(part, 4);
            part += __shfl_xor(part, 8);
            if (lrow == 0) atomicAdd(&rowsumL[(wm16 + i) * 16 + kq * 4 + r], part);
        }
    }
    __syncthreads();
    if (t < 128) atomicAdd(&rowsumG[(size_t)z * NTOK + m0 + t], rowsumL[t]);
}

// =====================================================================
// PV kernel (128x128, brick): AOt[n][o] = (sum_m E[n][m]*V[o][m]) / rowsum
// =====================================================================
__global__ __launch_bounds__(256) void pv_div_kernel(
    const u16* __restrict__ Ew, const u16* __restrict__ Vw,
    const float* __restrict__ rowsumG, u16* __restrict__ AOt)
{
    const int z   = blockIdx.x % B_;
    const int rem = blockIdx.x / B_;
    const int n0 = (rem % 4) * 128;              // o tiles, fast
    const int m0 = (rem / 4) * 128;              // token tiles
    const u16* A  = Ew + (size_t)z * NTOK * NTOK;
    const u16* Bp = Vw + (size_t)z * OCH * NTOK;

    __shared__ u16 As[8192];
    __shared__ u16 Bs[8192];

    const int t = threadIdx.x;
    const int w = t >> 6, ln = t & 63;
    const int wm16 = (w & 1) * 4, wn16 = (w >> 1) * 4;
    const int lrow = ln & 15, kq = ln >> 4;

    f32x4 acc[4][4] = {};

    KLOOP64(A, Bp, m0, n0, NTOK)

    u16* AO = AOt + (size_t)z * NTOK * OCH;
    const int offl = ((lrow >> 3) << 7) + (lrow & 7) + (kq << 5);
#pragma unroll
    for (int i = 0; i < 4; ++i) {
        const float4 rs4 = *(const float4*)(rowsumG + (size_t)z * NTOK + m0 + (wm16 + i) * 16 + kq * 4);
        const float inv0 = 1.0f / rs4.x, inv1 = 1.0f / rs4.y;
        const float inv2 = 1.0f / rs4.z, inv3 = 1.0f / rs4.w;
        u16* Crow = AO + ((size_t)((m0 >> 4) + wm16 + i) * (OCH >> 5) + (n0 >> 5)) * 512 + offl;
#pragma unroll
        for (int j = 0; j < 4; ++j) {
            u16* Cj = Crow + ((wn16 + j) >> 1) * 512 + ((j & 1) << 8);
            Cj[0]  = f2bf(acc[i][j][0] * inv0);
            Cj[8]  = f2bf(acc[i][j][1] * inv1);
            Cj[16] = f2bf(acc[i][j][2] * inv2);
            Cj[24] = f2bf(acc[i][j][3] * inv3);
        }
    }
}

// =====================================================================
extern "C" void kernel_launch(void* const* d_in, const int* in_sizes, int n_in,
                              void* d_out, int out_size, void* d_ws, size_t ws_size,
                              hipStream_t stream)
{
    const float* x  = (const float*)d_in[0];
    const float* Wq = (const float*)d_in[1];
    const float* bq = (const float*)d_in[2];
    const float* Wk = (const float*)d_in[3];
    const float* bk = (const float*)d_in[4];
    const float* Wv = (const float*)d_in[5];
    const float* bv = (const float*)d_in[6];
    const float* Wo = (const float*)d_in[7];
    const float* bo = (const float*)d_in[8];
    float* out = (float*)d_out;

    u16* ws = (u16*)d_ws;
    u16* Wqb = ws;
    u16* Wkb = Wqb + WQKV_SZ;
    u16* Wvb = Wkb + WQKV_SZ;
    u16* Wob = Wvb + WQKV_SZ;
    u16* xT  = Wob + WO_SZ;
    const size_t xtsz  = (size_t)B_ * NTOK * CIN;
    const size_t qkvsz = (size_t)B_ * NTOK * OCH;
    u16* Qt  = xT + xtsz;
    u16* Kt  = Qt + qkvsz;
    u16* Vw  = Kt + qkvsz;
    u16* Ew  = Vw + qkvsz;                          // B*N*N
    float* rowsumG = (float*)(Ew + (size_t)B_ * NTOK * NTOK);
    u16* AOt = Qt;                                  // alias: Qt dead after logits
    // total approx 157.5 MB

    dim3 blk(256);

    prep_w_kernel<<<dim3((CH_TOT + 255) / 256), blk, 0, stream>>>(
        Wq, Wk, Wv, Wo, Wqb, Wkb, Wvb, Wob);
    transpose_x_kernel<<<dim3(NTOK / 64, CIN / 64, B_), blk, 0, stream>>>(x, xT);
    hipMemsetAsync(rowsumG, 0, (size_t)B_ * NTOK * sizeof(float), stream);

    // Q & K merged: 4 o-tiles x 18 token-tiles x 16 (which*8+batch) = 1152
    qk_kernel<<<dim3(4 * 18 * 16), blk, 0, stream>>>(
        xT, Wqb, bq, Wkb, bk, Qt, Kt);
    // V[o][m] = Wv[o].xT[m] + bv[o]: 18 n-tiles (fast) x 4 m-tiles x 8 = 576
    gemm_kernel<1, u16><<<dim3(18 * 4 * B_), blk, 0, stream>>>(
        Wvb, xT, bv, Vw, CIN, NTOK, 0L, (long)NTOK * CIN, (long)OCH * NTOK, 18, B_);

    // E = exp(scale * Qt.Kt^T), rowsumG += row sums  (18x18x8 = 2592)
    logits_exp_kernel<<<dim3(18 * 18 * B_), blk, 0, stream>>>(Qt, Kt, Ew, rowsumG);

    // AOt = (E.V^T) / rowsum: 4 o-tiles (fast) x 18 token-tiles x 8 = 576
    pv_div_kernel<<<dim3(4 * 18 * B_), blk, 0, stream>>>(Ew, Vw, rowsumG, AOt);

    // out[p][n] = Wo[p].AOt[n] + bo[p]: 18 n-tiles (fast) x 4 p-tiles x 8 = 576
    gemm_kernel<1, float><<<dim3(18 * 4 * B_), blk, 0, stream>>>(
        Wob, AOt, bo, out, OCH, NTOK, 0L, (long)NTOK * OCH, (long)OCH * NTOK, 18, B_);
}